// Round 19
// baseline (2737.915 us; speedup 1.0000x reference)
//
#include <hip/hip_runtime.h>
#include <stdint.h>

typedef unsigned short u16;
typedef unsigned int u32;
typedef __bf16 bf16x8 __attribute__((ext_vector_type(8)));
typedef __bf16 bf16x4 __attribute__((ext_vector_type(4)));
typedef float f32x4 __attribute__((ext_vector_type(4)));

// ---------- helpers ----------
__device__ __forceinline__ u16 f2bf(float f) {
  u32 u = __builtin_bit_cast(u32, f);
  u32 r = (u + 0x7FFFu + ((u >> 16) & 1u)) >> 16;
  return (u16)r;
}

// ---------- weight fp32 -> bf16 (one layer; runs right before use = L2/L3 prefetch) ----------
__global__ __launch_bounds__(256)
void convert_w(const float* __restrict__ wq, const float* __restrict__ wk,
               const float* __restrict__ wv, const float* __restrict__ wo,
               const float* __restrict__ w1, const float* __restrict__ w2,
               u16* __restrict__ out) {
  size_t i = ((size_t)blockIdx.x * 256 + threadIdx.x) * 8;
  if (i >= 5505024) return;
  const float* src; size_t off;
  if (i < 589824)       { src = wq; off = i; }
  else if (i < 1179648) { src = wk; off = i - 589824; }
  else if (i < 1769472) { src = wv; off = i - 1179648; }
  else if (i < 2359296) { src = wo; off = i - 1769472; }
  else if (i < 3932160) { src = w1; off = i - 2359296; }
  else                  { src = w2; off = i - 3932160; }
  float4 a = *(const float4*)(src + off);
  float4 b = *(const float4*)(src + off + 4);
  uint4 o;
  o.x = (u32)f2bf(a.x) | ((u32)f2bf(a.y) << 16);
  o.y = (u32)f2bf(a.z) | ((u32)f2bf(a.w) << 16);
  o.z = (u32)f2bf(b.x) | ((u32)f2bf(b.y) << 16);
  o.w = (u32)f2bf(b.z) | ((u32)f2bf(b.w) << 16);
  *(uint4*)(out + i) = o;
}

// ---------- RMSNorm fp32 -> bf16 (D=768) ----------
__device__ __forceinline__ void rn_store4(u16* p, float4 v, float4 w, float sc) {
  u32 lo = (u32)f2bf(v.x * sc * w.x) | ((u32)f2bf(v.y * sc * w.y) << 16);
  u32 hi = (u32)f2bf(v.z * sc * w.z) | ((u32)f2bf(v.w * sc * w.w) << 16);
  *(uint2*)p = make_uint2(lo, hi);
}

__global__ __launch_bounds__(256)
void rmsnorm_k(const float* __restrict__ x, const float* __restrict__ w,
               u16* __restrict__ out) {
  const int tok = (blockIdx.x << 2) + (threadIdx.x >> 6);
  const int l = threadIdx.x & 63;
  const float* xr = x + (size_t)tok * 768;
  float4 v0 = *(const float4*)(xr + l * 4);
  float4 v1 = *(const float4*)(xr + 256 + l * 4);
  float4 v2 = *(const float4*)(xr + 512 + l * 4);
  float ss = v0.x*v0.x + v0.y*v0.y + v0.z*v0.z + v0.w*v0.w
           + v1.x*v1.x + v1.y*v1.y + v1.z*v1.z + v1.w*v1.w
           + v2.x*v2.x + v2.y*v2.y + v2.z*v2.z + v2.w*v2.w;
  ss += __shfl_xor(ss, 1);  ss += __shfl_xor(ss, 2);  ss += __shfl_xor(ss, 4);
  ss += __shfl_xor(ss, 8);  ss += __shfl_xor(ss, 16); ss += __shfl_xor(ss, 32);
  float sc = rsqrtf(ss * (1.f / 768.f) + 1e-12f);
  float4 w0 = *(const float4*)(w + l * 4);
  float4 w1v = *(const float4*)(w + 256 + l * 4);
  float4 w2v = *(const float4*)(w + 512 + l * 4);
  u16* o = out + (size_t)tok * 768;
  rn_store4(o + l * 4, v0, w0, sc);
  rn_store4(o + 256 + l * 4, v1, w1v, sc);
  rn_store4(o + 512 + l * 4, v2, w2v, sc);
}

// ---------- T1 chunked XCD swizzle ----------
__device__ __forceinline__ int xcd_swz(int bid, int nwg) {
  if (nwg & 7) return bid;
  return (bid & 7) * (nwg >> 3) + (bid >> 3);
}

// ---------- GEMM core (128x128 tile, 4 waves, m97 structure) ----------
#define GEMM_CORE(A_, W_, K_, m0_, n0_)                                             \
  for (int kt = 0; kt < (K_); kt += 64) {                                           \
    __syncthreads();                                                                \
    _Pragma("unroll")                                                               \
    for (int ii = 0; ii < 4; ++ii) {                                                \
      int issue = (w << 2) + ii;                                                    \
      int r = (issue << 3) + (l >> 3);                                              \
      int c = (l & 7) ^ (r & 7);                                                    \
      __builtin_amdgcn_global_load_lds((A_) + (size_t)((m0_) + r) * (K_) + kt + c * 8, \
                                       As + issue * 512, 16, 0, 0);                 \
      __builtin_amdgcn_global_load_lds((W_) + (size_t)((n0_) + r) * (K_) + kt + c * 8, \
                                       Ws + issue * 512, 16, 0, 0);                 \
    }                                                                               \
    __syncthreads();                                                                \
    _Pragma("unroll")                                                               \
    for (int kc = 0; kc < 2; ++kc) {                                                \
      int chunk = lg + (kc << 2);                                                   \
      bf16x8 af[4], bfr[4];                                                         \
      _Pragma("unroll")                                                             \
      for (int i = 0; i < 4; ++i) {                                                 \
        int mr = (wm << 6) + (i << 4) + ll;                                         \
        af[i] = *(const bf16x8*)((const char*)As + mr * 128 + ((chunk ^ (mr & 7)) << 4)); \
        int nr = (wn << 6) + (i << 4) + ll;                                         \
        bfr[i] = *(const bf16x8*)((const char*)Ws + nr * 128 + ((chunk ^ (nr & 7)) << 4)); \
      }                                                                             \
      _Pragma("unroll")                                                             \
      for (int i = 0; i < 4; ++i)                                                   \
        _Pragma("unroll")                                                           \
        for (int j = 0; j < 4; ++j)                                                 \
          acc[i][j] = __builtin_amdgcn_mfma_f32_16x16x32_bf16(af[i], bfr[j], acc[i][j], 0, 0, 0); \
    }                                                                               \
  }

// ---------- generic BT GEMM ----------
// (256,4): the 2nd launch-bounds arg empirically caps runtime waves/EU on this
// toolchain (all (256,2) kernels pinned at ~25% occupancy = 2 blocks/CU).
// VGPR use is 64 < 512/4=128, so no spill risk; LDS caps residency at 4 blocks/CU.
template<int EP>
__global__ __launch_bounds__(256, 4)
void gemm_bt(const u16* __restrict__ A, const u16* __restrict__ W,
             void* __restrict__ outp, const float* __restrict__ Res,
             int M, int N, int K) {
  __shared__ __align__(16) u16 As[128 * 64];
  __shared__ __align__(16) u16 Ws[128 * 64];
  const int tid = threadIdx.x;
  const int w = tid >> 6, l = tid & 63;
  const int lg = l >> 4, ll = l & 15;
  const int ntiles = N >> 7;
  const int wg = xcd_swz(blockIdx.x, gridDim.x);
  const int mt = wg / ntiles, nt = wg - mt * ntiles;
  const int m0 = mt << 7, n0 = nt << 7;
  const int wm = w >> 1, wn = w & 1;

  const f32x4 fz = {0.f, 0.f, 0.f, 0.f};
  f32x4 acc[4][4];
#pragma unroll
  for (int i = 0; i < 4; ++i)
#pragma unroll
    for (int j = 0; j < 4; ++j) acc[i][j] = fz;

  GEMM_CORE(A, W, K, m0, n0)

  const int g4 = lg << 2;
#pragma unroll
  for (int i = 0; i < 4; ++i) {
#pragma unroll
    for (int j = 0; j < 4; ++j) {
      int row0 = m0 + (wm << 6) + (i << 4) + g4;
      int col = n0 + (wn << 6) + (j << 4) + ll;
      f32x4 v = acc[i][j];
      if (EP == 0) {
        u16* o = (u16*)outp;
#pragma unroll
        for (int e = 0; e < 4; ++e) o[(size_t)(row0 + e) * N + col] = f2bf(v[e]);
      } else if (EP == 1) {
        float* o = (float*)outp;
#pragma unroll
        for (int e = 0; e < 4; ++e) {
          size_t idx = (size_t)(row0 + e) * N + col;
          o[idx] = Res[idx] + v[e];
        }
      } else {
        u16* o = (u16*)outp;
#pragma unroll
        for (int e = 0; e < 4; ++e) {
          float xx = v[e];
          o[(size_t)(row0 + e) * N + col] = f2bf(xx / (1.f + __expf(-xx)));
        }
      }
    }
  }
}

// ---------- 64x128-tile BT GEMM, fp32-residual epilogue (wo / ffn2) ----------
__global__ __launch_bounds__(256, 4)
void gemm_bt64(const u16* __restrict__ A, const u16* __restrict__ W,
               float* __restrict__ outp, const float* __restrict__ Res,
               int M, int N, int K) {
  __shared__ __align__(16) u16 As[64 * 64];
  __shared__ __align__(16) u16 Ws[128 * 64];
  const int tid = threadIdx.x;
  const int w = tid >> 6, l = tid & 63;
  const int lg = l >> 4, ll = l & 15;
  const int ntiles = N >> 7;
  const int wg = xcd_swz(blockIdx.x, gridDim.x);
  const int mt = wg / ntiles, nt = wg - mt * ntiles;
  const int m0 = mt << 6, n0 = nt << 7;
  const int wm = w >> 1, wn = w & 1;

  const f32x4 fz = {0.f, 0.f, 0.f, 0.f};
  f32x4 acc[2][4];
#pragma unroll
  for (int i = 0; i < 2; ++i)
#pragma unroll
    for (int j = 0; j < 4; ++j) acc[i][j] = fz;

  for (int kt = 0; kt < K; kt += 64) {
    __syncthreads();
#pragma unroll
    for (int ii = 0; ii < 6; ++ii) {
      int issue = w * 6 + ii;
      if (issue < 8) {
        int r = (issue << 3) + (l >> 3);
        int c = (l & 7) ^ (r & 7);
        __builtin_amdgcn_global_load_lds(A + (size_t)(m0 + r) * K + kt + c * 8,
                                         As + issue * 512, 16, 0, 0);
      } else {
        int is2 = issue - 8;
        int r = (is2 << 3) + (l >> 3);
        int c = (l & 7) ^ (r & 7);
        __builtin_amdgcn_global_load_lds(W + (size_t)(n0 + r) * K + kt + c * 8,
                                         Ws + is2 * 512, 16, 0, 0);
      }
    }
    __syncthreads();
#pragma unroll
    for (int kc = 0; kc < 2; ++kc) {
      int chunk = lg + (kc << 2);
      bf16x8 af[2], bfr[4];
#pragma unroll
      for (int i = 0; i < 2; ++i) {
        int mr = (wm << 5) + (i << 4) + ll;
        af[i] = *(const bf16x8*)((const char*)As + mr * 128 + ((chunk ^ (mr & 7)) << 4));
      }
#pragma unroll
      for (int j = 0; j < 4; ++j) {
        int nr = (wn << 6) + (j << 4) + ll;
        bfr[j] = *(const bf16x8*)((const char*)Ws + nr * 128 + ((chunk ^ (nr & 7)) << 4));
      }
#pragma unroll
      for (int i = 0; i < 2; ++i)
#pragma unroll
        for (int j = 0; j < 4; ++j)
          acc[i][j] = __builtin_amdgcn_mfma_f32_16x16x32_bf16(af[i], bfr[j], acc[i][j], 0, 0, 0);
    }
  }

  const int g4 = lg << 2;
#pragma unroll
  for (int i = 0; i < 2; ++i) {
#pragma unroll
    for (int j = 0; j < 4; ++j) {
      int row0 = m0 + (wm << 5) + (i << 4) + g4;
      int col = n0 + (wn << 6) + (j << 4) + ll;
      f32x4 v = acc[i][j];
#pragma unroll
      for (int e = 0; e < 4; ++e) {
        size_t idx = (size_t)(row0 + e) * N + col;
        outp[idx] = Res[idx] + v[e];
      }
    }
  }
}

// ---------- fused QKV GEMM ----------
__global__ __launch_bounds__(256, 4)
void gemm_qkv(const u16* __restrict__ A, const u16* __restrict__ W,
              u16* __restrict__ Qo, u16* __restrict__ Ko, u16* __restrict__ Vo) {
  __shared__ __align__(16) u16 As[128 * 64];
  __shared__ __align__(16) u16 Ws[128 * 64];
  const int tid = threadIdx.x;
  const int w = tid >> 6, l = tid & 63;
  const int lg = l >> 4, ll = l & 15;
  const int wg = xcd_swz(blockIdx.x, 1152);
  const int mt = wg / 18, nt = wg - mt * 18;
  const int m0 = mt << 7, n0 = nt << 7;
  const int wm = w >> 1, wn = w & 1;
  const int K = 768;

  const f32x4 fz = {0.f, 0.f, 0.f, 0.f};
  f32x4 acc[4][4];
#pragma unroll
  for (int i = 0; i < 4; ++i)
#pragma unroll
    for (int j = 0; j < 4; ++j) acc[i][j] = fz;

  GEMM_CORE(A, W, K, m0, n0)

  const int g4 = lg << 2;
#pragma unroll
  for (int i = 0; i < 4; ++i) {
#pragma unroll
    for (int j = 0; j < 4; ++j) {
      int row0 = m0 + (wm << 6) + (i << 4) + g4;
      int col = n0 + (wn << 6) + (j << 4) + ll;
      f32x4 v = acc[i][j];
      if (nt < 12) {
        u16* o = (nt < 6) ? Qo : Ko;
        int c = (nt < 6) ? col : (col - 768);
#pragma unroll
        for (int e = 0; e < 4; ++e) o[(size_t)(row0 + e) * 768 + c] = f2bf(v[e]);
      } else {
        int c = col - 1536;
        int vrow = ((row0 >> 10) * 768) + c;
        u32 lo = (u32)f2bf(v[0]) | ((u32)f2bf(v[1]) << 16);
        u32 hi = (u32)f2bf(v[2]) | ((u32)f2bf(v[3]) << 16);
        *(uint2*)(Vo + ((size_t)vrow << 10) + (row0 & 1023)) = make_uint2(lo, hi);
      }
    }
  }
}

// ---------- flash attention: QBLK=64, LDS-staged K/V, P in Ks, defer-max ----------
#define AT_SYNC  asm volatile("s_waitcnt lgkmcnt(0)" ::: "memory"); \
                 __builtin_amdgcn_s_barrier();                      \
                 asm volatile("" ::: "memory")
__global__ __launch_bounds__(256, 4)
void attn_kernel(const u16* __restrict__ Q, const u16* __restrict__ Kg,
                 const u16* __restrict__ Vt, u16* __restrict__ Og) {
  __shared__ __align__(16) __bf16 Ks[128 * 64];   // K tile; doubles as P after QK^T
  __shared__ __align__(16) __bf16 Vs[64 * 128];

  const int tid = threadIdx.x;
  const int w = tid >> 6, l = tid & 63;
  const int lg = l >> 4, ll = l & 15;
  const int bid = blockIdx.x;
  const int qt = bid / 96;          // XCD-locality remap (96 % 8 == 0)
  const int bh = bid - (bid / 96) * 96;
  const int b = bh / 12, hh = bh - b * 12;
  const float SC = 0.125f * 1.44269504f;

  __bf16* Pw = Ks + (w << 11);

  bf16x8 qf[2];
  const int tq0 = (b << 10) + (qt << 6) + (w << 4);
#pragma unroll
  for (int kc = 0; kc < 2; ++kc)
    qf[kc] = *(const bf16x8*)(Q + (size_t)(tq0 + ll) * 768 + hh * 64 + kc * 32 + lg * 8);

  bf16x8 kp[4], vp[4];
#define ISSUE_KV(t_)                                                                  \
  { _Pragma("unroll")                                                                 \
    for (int ii = 0; ii < 4; ++ii) {                                                  \
      int issue = (w << 2) + ii;                                                      \
      int r = (issue << 3) + (l >> 3);                                                \
      int c = (l & 7) ^ (r & 7);                                                      \
      kp[ii] = *(const bf16x8*)(Kg + (size_t)((b << 10) + ((t_) << 7) + r) * 768 + hh * 64 + c * 8); \
      int rv = (issue << 2) + (l >> 4);                                               \
      int cv = ll ^ (rv & 7);                                                         \
      vp[ii] = *(const bf16x8*)(Vt + (size_t)((bh << 6) + rv) * 1024 + ((t_) << 7) + cv * 8); \
    } }
#define WRITE_KV                                                                      \
  { _Pragma("unroll")                                                                 \
    for (int ii = 0; ii < 4; ++ii) {                                                  \
      int issue = (w << 2) + ii;                                                      \
      *(bf16x8*)((char*)Ks + issue * 1024 + l * 16) = kp[ii];                         \
      *(bf16x8*)((char*)Vs + issue * 1024 + l * 16) = vp[ii];                         \
    } }

  const f32x4 fz = {0.f, 0.f, 0.f, 0.f};
  f32x4 oacc[4];
#pragma unroll
  for (int i = 0; i < 4; ++i) oacc[i] = fz;
  float mrow = -1e30f, lrow = 0.f;

  ISSUE_KV(0);
  WRITE_KV;
  AT_SYNC;

  for (int kt = 0; kt < 8; ++kt) {
    if (kt < 7) ISSUE_KV(kt + 1);

    f32x4 sa[8];
#pragma unroll
    for (int fn = 0; fn < 8; ++fn) sa[fn] = fz;
    __builtin_amdgcn_s_setprio(1);
#pragma unroll
    for (int kc = 0; kc < 2; ++kc) {
      int chunk = lg + (kc << 2);
      bf16x8 kb[8];
#pragma unroll
      for (int fn = 0; fn < 8; ++fn) {
        int nr = (fn << 4) + ll;
        kb[fn] = *(const bf16x8*)((const char*)Ks + nr * 128 + ((chunk ^ (nr & 7)) << 4));
      }
#pragma unroll
      for (int fn = 0; fn < 8; ++fn)
        sa[fn] = __builtin_amdgcn_mfma_f32_16x16x32_bf16(kb[fn], qf[kc], sa[fn], 0, 0, 0);
    }
    __builtin_amdgcn_s_setprio(0);

    AT_SYNC;  // all waves done reading Ks -> reuse as P

    f32x4 vm = sa[0];
#pragma unroll
    for (int fn = 1; fn < 8; ++fn) {
#pragma unroll
      for (int e = 0; e < 4; ++e) vm[e] = fmaxf(vm[e], sa[fn][e]);
    }
    float mx = fmaxf(fmaxf(vm[0], vm[1]), fmaxf(vm[2], vm[3]));
    mx = fmaxf(mx, __shfl_xor(mx, 16));
    mx = fmaxf(mx, __shfl_xor(mx, 32));

    // T13 defer-max: skip rescale when per-tile max growth <= 8
    float scal = 1.f;
    bool rescale = !__all(mx - mrow <= 8.f);
    if (rescale) {
      float mnew = fmaxf(mrow, mx);
      scal = __builtin_amdgcn_exp2f(SC * (mrow - mnew));
#pragma unroll
      for (int fd = 0; fd < 4; ++fd) oacc[fd] *= scal;
      mrow = mnew;
    }
    float c2 = mrow * SC;

    f32x4 vsum = fz;
#pragma unroll
    for (int fn = 0; fn < 8; ++fn) {
      f32x4 p;
#pragma unroll
      for (int e = 0; e < 4; ++e)
        p[e] = __builtin_amdgcn_exp2f(__builtin_fmaf(SC, sa[fn][e], -c2));
      vsum += p;
      bf16x4 pv4;
#pragma unroll
      for (int e = 0; e < 4; ++e) pv4[e] = (__bf16)p[e];
      int chunk = (fn << 1) + (lg >> 1);
      *(bf16x4*)((char*)Pw + ll * 256 + ((chunk ^ (ll & 7)) << 4) + ((lg & 1) << 3)) = pv4;
    }
    float rs = (vsum[0] + vsum[1]) + (vsum[2] + vsum[3]);
    rs += __shfl_xor(rs, 16);
    rs += __shfl_xor(rs, 32);
    lrow = lrow * scal + rs;

    asm volatile("" ::: "memory");

    __builtin_amdgcn_s_setprio(1);
#pragma unroll
    for (int ch = 0; ch < 4; ++ch) {
      int chunk = lg + (ch << 2);
      bf16x8 pb = *(const bf16x8*)((const char*)Pw + ll * 256 + ((chunk ^ (ll & 7)) << 4));
#pragma unroll
      for (int fd = 0; fd < 4; ++fd) {
        int dr = (fd << 4) + ll;
        bf16x8 av = *(const bf16x8*)((const char*)Vs + dr * 256 + ((chunk ^ (dr & 7)) << 4));
        oacc[fd] = __builtin_amdgcn_mfma_f32_16x16x32_bf16(av, pb, oacc[fd], 0, 0, 0);
      }
    }
    __builtin_amdgcn_s_setprio(0);

    if (kt < 7) {
      AT_SYNC;      // all waves done reading Vs/P
      WRITE_KV;     // vmcnt wait lands here (late)
      AT_SYNC;
    }
  }
#undef ISSUE_KV
#undef WRITE_KV

  float inv = 1.f / lrow;
#pragma unroll
  for (int fd = 0; fd < 4; ++fd) {
    f32x4 v = oacc[fd];
    int d0 = (fd << 4) + (lg << 2);
    u16* o = Og + (size_t)(tq0 + ll) * 768 + hh * 64 + d0;
    u32 lo = (u32)f2bf(v[0] * inv) | ((u32)f2bf(v[1] * inv) << 16);
    u32 hi = (u32)f2bf(v[2] * inv) | ((u32)f2bf(v[3] * inv) << 16);
    *(uint2*)o = make_uint2(lo, hi);
  }
}

// ---------- launch ----------
extern "C" void kernel_launch(void* const* d_in, const int* in_sizes, int n_in,
                              void* d_out, int out_size, void* d_ws, size_t ws_size,
                              hipStream_t stream) {
  const float* x = (const float*)d_in[0];
  const float* wq = (const float*)d_in[1];
  const float* wk = (const float*)d_in[2];
  const float* wv = (const float*)d_in[3];
  const float* wo = (const float*)d_in[4];
  const float* w1 = (const float*)d_in[5];
  const float* w2 = (const float*)d_in[6];
  const float* anw = (const float*)d_in[7];
  const float* fnw = (const float*)d_in[8];

  char* ws = (char*)d_ws;
  float* h    = (float*)(ws);
  u16* xn     = (u16*)(ws + 25165824);
  u16* qb     = (u16*)(ws + 37748736);
  u16* kb     = (u16*)(ws + 50331648);
  u16* vt     = (u16*)(ws + 62914560);
  u16* ff1    = (u16*)(ws + 75497472);
  u16* wbuf   = (u16*)(ws + 109051904);

  for (int L = 0; L < 12; ++L) {
    // per-layer convert = L2/L3 prefetch of this layer's weights
    convert_w<<<2688, 256, 0, stream>>>(
        wq + (size_t)L * 589824, wk + (size_t)L * 589824,
        wv + (size_t)L * 589824, wo + (size_t)L * 589824,
        w1 + (size_t)L * 1572864, w2 + (size_t)L * 1572864, wbuf);
    const float* hin = (L == 0) ? x : h;
    rmsnorm_k<<<2048, 256, 0, stream>>>(hin, anw + L * 768, xn);
    gemm_qkv<<<1152, 256, 0, stream>>>(xn, wbuf, qb, kb, vt);
    attn_kernel<<<1536, 256, 0, stream>>>(qb, kb, vt, qb);
    gemm_bt64<<<768, 256, 0, stream>>>(qb, wbuf + 1769472, h, hin, 8192, 768, 768);
    rmsnorm_k<<<2048, 256, 0, stream>>>(h, fnw + L * 768, xn);
    gemm_bt<2><<<1024, 256, 0, stream>>>(xn, wbuf + 2359296, ff1, nullptr, 8192, 2048, 768);
    float* outw = (L == 11) ? (float*)d_out : h;
    gemm_bt64<<<768, 256, 0, stream>>>(ff1, wbuf + 3932160, outw, h, 8192, 768, 2048);
  }
}

// Round 20
// 2502.816 us; speedup vs baseline: 1.0939x; 1.0939x over previous
//
#include <hip/hip_runtime.h>
#include <stdint.h>

typedef unsigned short u16;
typedef unsigned int u32;
typedef __bf16 bf16x8 __attribute__((ext_vector_type(8)));
typedef __bf16 bf16x4 __attribute__((ext_vector_type(4)));
typedef float f32x4 __attribute__((ext_vector_type(4)));

// ---------- helpers ----------
__device__ __forceinline__ u16 f2bf(float f) {
  u32 u = __builtin_bit_cast(u32, f);
  u32 r = (u + 0x7FFFu + ((u >> 16) & 1u)) >> 16;
  return (u16)r;
}

// ---------- weight fp32 -> bf16 (one layer; runs right before use = L2/L3 prefetch) ----------
__global__ __launch_bounds__(256)
void convert_w(const float* __restrict__ wq, const float* __restrict__ wk,
               const float* __restrict__ wv, const float* __restrict__ wo,
               const float* __restrict__ w1, const float* __restrict__ w2,
               u16* __restrict__ out) {
  size_t i = ((size_t)blockIdx.x * 256 + threadIdx.x) * 8;
  if (i >= 5505024) return;
  const float* src; size_t off;
  if (i < 589824)       { src = wq; off = i; }
  else if (i < 1179648) { src = wk; off = i - 589824; }
  else if (i < 1769472) { src = wv; off = i - 1179648; }
  else if (i < 2359296) { src = wo; off = i - 1769472; }
  else if (i < 3932160) { src = w1; off = i - 2359296; }
  else                  { src = w2; off = i - 3932160; }
  float4 a = *(const float4*)(src + off);
  float4 b = *(const float4*)(src + off + 4);
  uint4 o;
  o.x = (u32)f2bf(a.x) | ((u32)f2bf(a.y) << 16);
  o.y = (u32)f2bf(a.z) | ((u32)f2bf(a.w) << 16);
  o.z = (u32)f2bf(b.x) | ((u32)f2bf(b.y) << 16);
  o.w = (u32)f2bf(b.z) | ((u32)f2bf(b.w) << 16);
  *(uint4*)(out + i) = o;
}

// ---------- RMSNorm fp32 -> bf16 (D=768) ----------
__device__ __forceinline__ void rn_store4(u16* p, float4 v, float4 w, float sc) {
  u32 lo = (u32)f2bf(v.x * sc * w.x) | ((u32)f2bf(v.y * sc * w.y) << 16);
  u32 hi = (u32)f2bf(v.z * sc * w.z) | ((u32)f2bf(v.w * sc * w.w) << 16);
  *(uint2*)p = make_uint2(lo, hi);
}

__global__ __launch_bounds__(256)
void rmsnorm_k(const float* __restrict__ x, const float* __restrict__ w,
               u16* __restrict__ out) {
  const int tok = (blockIdx.x << 2) + (threadIdx.x >> 6);
  const int l = threadIdx.x & 63;
  const float* xr = x + (size_t)tok * 768;
  float4 v0 = *(const float4*)(xr + l * 4);
  float4 v1 = *(const float4*)(xr + 256 + l * 4);
  float4 v2 = *(const float4*)(xr + 512 + l * 4);
  float ss = v0.x*v0.x + v0.y*v0.y + v0.z*v0.z + v0.w*v0.w
           + v1.x*v1.x + v1.y*v1.y + v1.z*v1.z + v1.w*v1.w
           + v2.x*v2.x + v2.y*v2.y + v2.z*v2.z + v2.w*v2.w;
  ss += __shfl_xor(ss, 1);  ss += __shfl_xor(ss, 2);  ss += __shfl_xor(ss, 4);
  ss += __shfl_xor(ss, 8);  ss += __shfl_xor(ss, 16); ss += __shfl_xor(ss, 32);
  float sc = rsqrtf(ss * (1.f / 768.f) + 1e-12f);
  float4 w0 = *(const float4*)(w + l * 4);
  float4 w1v = *(const float4*)(w + 256 + l * 4);
  float4 w2v = *(const float4*)(w + 512 + l * 4);
  u16* o = out + (size_t)tok * 768;
  rn_store4(o + l * 4, v0, w0, sc);
  rn_store4(o + 256 + l * 4, v1, w1v, sc);
  rn_store4(o + 512 + l * 4, v2, w2v, sc);
}

// ---------- T1 chunked XCD swizzle ----------
__device__ __forceinline__ int xcd_swz(int bid, int nwg) {
  if (nwg & 7) return bid;
  return (bid & 7) * (nwg >> 3) + (bid >> 3);
}

// ---------- GEMM core (128x128 tile, 4 waves, m97 structure) ----------
#define GEMM_CORE(A_, W_, K_, m0_, n0_)                                             \
  for (int kt = 0; kt < (K_); kt += 64) {                                           \
    __syncthreads();                                                                \
    _Pragma("unroll")                                                               \
    for (int ii = 0; ii < 4; ++ii) {                                                \
      int issue = (w << 2) + ii;                                                    \
      int r = (issue << 3) + (l >> 3);                                              \
      int c = (l & 7) ^ (r & 7);                                                    \
      __builtin_amdgcn_global_load_lds((A_) + (size_t)((m0_) + r) * (K_) + kt + c * 8, \
                                       As + issue * 512, 16, 0, 0);                 \
      __builtin_amdgcn_global_load_lds((W_) + (size_t)((n0_) + r) * (K_) + kt + c * 8, \
                                       Ws + issue * 512, 16, 0, 0);                 \
    }                                                                               \
    __syncthreads();                                                                \
    _Pragma("unroll")                                                               \
    for (int kc = 0; kc < 2; ++kc) {                                                \
      int chunk = lg + (kc << 2);                                                   \
      bf16x8 af[4], bfr[4];                                                         \
      _Pragma("unroll")                                                             \
      for (int i = 0; i < 4; ++i) {                                                 \
        int mr = (wm << 6) + (i << 4) + ll;                                         \
        af[i] = *(const bf16x8*)((const char*)As + mr * 128 + ((chunk ^ (mr & 7)) << 4)); \
        int nr = (wn << 6) + (i << 4) + ll;                                         \
        bfr[i] = *(const bf16x8*)((const char*)Ws + nr * 128 + ((chunk ^ (nr & 7)) << 4)); \
      }                                                                             \
      _Pragma("unroll")                                                             \
      for (int i = 0; i < 4; ++i)                                                   \
        _Pragma("unroll")                                                           \
        for (int j = 0; j < 4; ++j)                                                 \
          acc[i][j] = __builtin_amdgcn_mfma_f32_16x16x32_bf16(af[i], bfr[j], acc[i][j], 0, 0, 0); \
    }                                                                               \
  }

// ---------- generic BT GEMM ----------
// (256,4): r19 A/B showed GEMMs at (256,4) are net ~-50 us vs (256,2) (VGPR 64 fits,
// no spill). Attn at (256,4) SPILLED (VGPR clamp 64 < 76 live) -> attn stays (256,2).
template<int EP>
__global__ __launch_bounds__(256, 4)
void gemm_bt(const u16* __restrict__ A, const u16* __restrict__ W,
             void* __restrict__ outp, const float* __restrict__ Res,
             int M, int N, int K) {
  __shared__ __align__(16) u16 As[128 * 64];
  __shared__ __align__(16) u16 Ws[128 * 64];
  const int tid = threadIdx.x;
  const int w = tid >> 6, l = tid & 63;
  const int lg = l >> 4, ll = l & 15;
  const int ntiles = N >> 7;
  const int wg = xcd_swz(blockIdx.x, gridDim.x);
  const int mt = wg / ntiles, nt = wg - mt * ntiles;
  const int m0 = mt << 7, n0 = nt << 7;
  const int wm = w >> 1, wn = w & 1;

  const f32x4 fz = {0.f, 0.f, 0.f, 0.f};
  f32x4 acc[4][4];
#pragma unroll
  for (int i = 0; i < 4; ++i)
#pragma unroll
    for (int j = 0; j < 4; ++j) acc[i][j] = fz;

  GEMM_CORE(A, W, K, m0, n0)

  const int g4 = lg << 2;
#pragma unroll
  for (int i = 0; i < 4; ++i) {
#pragma unroll
    for (int j = 0; j < 4; ++j) {
      int row0 = m0 + (wm << 6) + (i << 4) + g4;
      int col = n0 + (wn << 6) + (j << 4) + ll;
      f32x4 v = acc[i][j];
      if (EP == 0) {
        u16* o = (u16*)outp;
#pragma unroll
        for (int e = 0; e < 4; ++e) o[(size_t)(row0 + e) * N + col] = f2bf(v[e]);
      } else if (EP == 1) {
        float* o = (float*)outp;
#pragma unroll
        for (int e = 0; e < 4; ++e) {
          size_t idx = (size_t)(row0 + e) * N + col;
          o[idx] = Res[idx] + v[e];
        }
      } else {
        u16* o = (u16*)outp;
#pragma unroll
        for (int e = 0; e < 4; ++e) {
          float xx = v[e];
          o[(size_t)(row0 + e) * N + col] = f2bf(xx / (1.f + __expf(-xx)));
        }
      }
    }
  }
}

// ---------- 64x128-tile BT GEMM, fp32-residual epilogue (wo / ffn2) ----------
__global__ __launch_bounds__(256, 4)
void gemm_bt64(const u16* __restrict__ A, const u16* __restrict__ W,
               float* __restrict__ outp, const float* __restrict__ Res,
               int M, int N, int K) {
  __shared__ __align__(16) u16 As[64 * 64];
  __shared__ __align__(16) u16 Ws[128 * 64];
  const int tid = threadIdx.x;
  const int w = tid >> 6, l = tid & 63;
  const int lg = l >> 4, ll = l & 15;
  const int ntiles = N >> 7;
  const int wg = xcd_swz(blockIdx.x, gridDim.x);
  const int mt = wg / ntiles, nt = wg - mt * ntiles;
  const int m0 = mt << 6, n0 = nt << 7;
  const int wm = w >> 1, wn = w & 1;

  const f32x4 fz = {0.f, 0.f, 0.f, 0.f};
  f32x4 acc[2][4];
#pragma unroll
  for (int i = 0; i < 2; ++i)
#pragma unroll
    for (int j = 0; j < 4; ++j) acc[i][j] = fz;

  for (int kt = 0; kt < K; kt += 64) {
    __syncthreads();
#pragma unroll
    for (int ii = 0; ii < 6; ++ii) {
      int issue = w * 6 + ii;
      if (issue < 8) {
        int r = (issue << 3) + (l >> 3);
        int c = (l & 7) ^ (r & 7);
        __builtin_amdgcn_global_load_lds(A + (size_t)(m0 + r) * K + kt + c * 8,
                                         As + issue * 512, 16, 0, 0);
      } else {
        int is2 = issue - 8;
        int r = (is2 << 3) + (l >> 3);
        int c = (l & 7) ^ (r & 7);
        __builtin_amdgcn_global_load_lds(W + (size_t)(n0 + r) * K + kt + c * 8,
                                         Ws + is2 * 512, 16, 0, 0);
      }
    }
    __syncthreads();
#pragma unroll
    for (int kc = 0; kc < 2; ++kc) {
      int chunk = lg + (kc << 2);
      bf16x8 af[2], bfr[4];
#pragma unroll
      for (int i = 0; i < 2; ++i) {
        int mr = (wm << 5) + (i << 4) + ll;
        af[i] = *(const bf16x8*)((const char*)As + mr * 128 + ((chunk ^ (mr & 7)) << 4));
      }
#pragma unroll
      for (int j = 0; j < 4; ++j) {
        int nr = (wn << 6) + (j << 4) + ll;
        bfr[j] = *(const bf16x8*)((const char*)Ws + nr * 128 + ((chunk ^ (nr & 7)) << 4));
      }
#pragma unroll
      for (int i = 0; i < 2; ++i)
#pragma unroll
        for (int j = 0; j < 4; ++j)
          acc[i][j] = __builtin_amdgcn_mfma_f32_16x16x32_bf16(af[i], bfr[j], acc[i][j], 0, 0, 0);
    }
  }

  const int g4 = lg << 2;
#pragma unroll
  for (int i = 0; i < 2; ++i) {
#pragma unroll
    for (int j = 0; j < 4; ++j) {
      int row0 = m0 + (wm << 5) + (i << 4) + g4;
      int col = n0 + (wn << 6) + (j << 4) + ll;
      f32x4 v = acc[i][j];
#pragma unroll
      for (int e = 0; e < 4; ++e) {
        size_t idx = (size_t)(row0 + e) * N + col;
        outp[idx] = Res[idx] + v[e];
      }
    }
  }
}

// ---------- fused QKV GEMM ----------
__global__ __launch_bounds__(256, 4)
void gemm_qkv(const u16* __restrict__ A, const u16* __restrict__ W,
              u16* __restrict__ Qo, u16* __restrict__ Ko, u16* __restrict__ Vo) {
  __shared__ __align__(16) u16 As[128 * 64];
  __shared__ __align__(16) u16 Ws[128 * 64];
  const int tid = threadIdx.x;
  const int w = tid >> 6, l = tid & 63;
  const int lg = l >> 4, ll = l & 15;
  const int wg = xcd_swz(blockIdx.x, 1152);
  const int mt = wg / 18, nt = wg - mt * 18;
  const int m0 = mt << 7, n0 = nt << 7;
  const int wm = w >> 1, wn = w & 1;
  const int K = 768;

  const f32x4 fz = {0.f, 0.f, 0.f, 0.f};
  f32x4 acc[4][4];
#pragma unroll
  for (int i = 0; i < 4; ++i)
#pragma unroll
    for (int j = 0; j < 4; ++j) acc[i][j] = fz;

  GEMM_CORE(A, W, K, m0, n0)

  const int g4 = lg << 2;
#pragma unroll
  for (int i = 0; i < 4; ++i) {
#pragma unroll
    for (int j = 0; j < 4; ++j) {
      int row0 = m0 + (wm << 6) + (i << 4) + g4;
      int col = n0 + (wn << 6) + (j << 4) + ll;
      f32x4 v = acc[i][j];
      if (nt < 12) {
        u16* o = (nt < 6) ? Qo : Ko;
        int c = (nt < 6) ? col : (col - 768);
#pragma unroll
        for (int e = 0; e < 4; ++e) o[(size_t)(row0 + e) * 768 + c] = f2bf(v[e]);
      } else {
        int c = col - 1536;
        int vrow = ((row0 >> 10) * 768) + c;
        u32 lo = (u32)f2bf(v[0]) | ((u32)f2bf(v[1]) << 16);
        u32 hi = (u32)f2bf(v[2]) | ((u32)f2bf(v[3]) << 16);
        *(uint2*)(Vo + ((size_t)vrow << 10) + (row0 & 1023)) = make_uint2(lo, hi);
      }
    }
  }
}

// ---------- flash attention: QBLK=64, LDS-staged K/V, P in Ks, defer-max ----------
// (256,2): proven no-spill point (VGPR 76). (256,4) clamps to 64 VGPR -> spills (r19).
#define AT_SYNC  asm volatile("s_waitcnt lgkmcnt(0)" ::: "memory"); \
                 __builtin_amdgcn_s_barrier();                      \
                 asm volatile("" ::: "memory")
__global__ __launch_bounds__(256, 2)
void attn_kernel(const u16* __restrict__ Q, const u16* __restrict__ Kg,
                 const u16* __restrict__ Vt, u16* __restrict__ Og) {
  __shared__ __align__(16) __bf16 Ks[128 * 64];   // K tile; doubles as P after QK^T
  __shared__ __align__(16) __bf16 Vs[64 * 128];

  const int tid = threadIdx.x;
  const int w = tid >> 6, l = tid & 63;
  const int lg = l >> 4, ll = l & 15;
  const int bid = blockIdx.x;
  const int qt = bid / 96;          // XCD-locality remap (96 % 8 == 0)
  const int bh = bid - (bid / 96) * 96;
  const int b = bh / 12, hh = bh - b * 12;
  const float SC = 0.125f * 1.44269504f;

  __bf16* Pw = Ks + (w << 11);

  bf16x8 qf[2];
  const int tq0 = (b << 10) + (qt << 6) + (w << 4);
#pragma unroll
  for (int kc = 0; kc < 2; ++kc)
    qf[kc] = *(const bf16x8*)(Q + (size_t)(tq0 + ll) * 768 + hh * 64 + kc * 32 + lg * 8);

  bf16x8 kp[4], vp[4];
#define ISSUE_KV(t_)                                                                  \
  { _Pragma("unroll")                                                                 \
    for (int ii = 0; ii < 4; ++ii) {                                                  \
      int issue = (w << 2) + ii;                                                      \
      int r = (issue << 3) + (l >> 3);                                                \
      int c = (l & 7) ^ (r & 7);                                                      \
      kp[ii] = *(const bf16x8*)(Kg + (size_t)((b << 10) + ((t_) << 7) + r) * 768 + hh * 64 + c * 8); \
      int rv = (issue << 2) + (l >> 4);                                               \
      int cv = ll ^ (rv & 7);                                                         \
      vp[ii] = *(const bf16x8*)(Vt + (size_t)((bh << 6) + rv) * 1024 + ((t_) << 7) + cv * 8); \
    } }
#define WRITE_KV                                                                      \
  { _Pragma("unroll")                                                                 \
    for (int ii = 0; ii < 4; ++ii) {                                                  \
      int issue = (w << 2) + ii;                                                      \
      *(bf16x8*)((char*)Ks + issue * 1024 + l * 16) = kp[ii];                         \
      *(bf16x8*)((char*)Vs + issue * 1024 + l * 16) = vp[ii];                         \
    } }

  const f32x4 fz = {0.f, 0.f, 0.f, 0.f};
  f32x4 oacc[4];
#pragma unroll
  for (int i = 0; i < 4; ++i) oacc[i] = fz;
  float mrow = -1e30f, lrow = 0.f;

  ISSUE_KV(0);
  WRITE_KV;
  AT_SYNC;

  for (int kt = 0; kt < 8; ++kt) {
    if (kt < 7) ISSUE_KV(kt + 1);

    f32x4 sa[8];
#pragma unroll
    for (int fn = 0; fn < 8; ++fn) sa[fn] = fz;
    __builtin_amdgcn_s_setprio(1);
#pragma unroll
    for (int kc = 0; kc < 2; ++kc) {
      int chunk = lg + (kc << 2);
      bf16x8 kb[8];
#pragma unroll
      for (int fn = 0; fn < 8; ++fn) {
        int nr = (fn << 4) + ll;
        kb[fn] = *(const bf16x8*)((const char*)Ks + nr * 128 + ((chunk ^ (nr & 7)) << 4));
      }
#pragma unroll
      for (int fn = 0; fn < 8; ++fn)
        sa[fn] = __builtin_amdgcn_mfma_f32_16x16x32_bf16(kb[fn], qf[kc], sa[fn], 0, 0, 0);
    }
    __builtin_amdgcn_s_setprio(0);

    AT_SYNC;  // all waves done reading Ks -> reuse as P

    f32x4 vm = sa[0];
#pragma unroll
    for (int fn = 1; fn < 8; ++fn) {
#pragma unroll
      for (int e = 0; e < 4; ++e) vm[e] = fmaxf(vm[e], sa[fn][e]);
    }
    float mx = fmaxf(fmaxf(vm[0], vm[1]), fmaxf(vm[2], vm[3]));
    mx = fmaxf(mx, __shfl_xor(mx, 16));
    mx = fmaxf(mx, __shfl_xor(mx, 32));

    // T13 defer-max: skip rescale when per-tile max growth <= 8
    float scal = 1.f;
    bool rescale = !__all(mx - mrow <= 8.f);
    if (rescale) {
      float mnew = fmaxf(mrow, mx);
      scal = __builtin_amdgcn_exp2f(SC * (mrow - mnew));
#pragma unroll
      for (int fd = 0; fd < 4; ++fd) oacc[fd] *= scal;
      mrow = mnew;
    }
    float c2 = mrow * SC;

    f32x4 vsum = fz;
#pragma unroll
    for (int fn = 0; fn < 8; ++fn) {
      f32x4 p;
#pragma unroll
      for (int e = 0; e < 4; ++e)
        p[e] = __builtin_amdgcn_exp2f(__builtin_fmaf(SC, sa[fn][e], -c2));
      vsum += p;
      bf16x4 pv4;
#pragma unroll
      for (int e = 0; e < 4; ++e) pv4[e] = (__bf16)p[e];
      int chunk = (fn << 1) + (lg >> 1);
      *(bf16x4*)((char*)Pw + ll * 256 + ((chunk ^ (ll & 7)) << 4) + ((lg & 1) << 3)) = pv4;
    }
    float rs = (vsum[0] + vsum[1]) + (vsum[2] + vsum[3]);
    rs += __shfl_xor(rs, 16);
    rs += __shfl_xor(rs, 32);
    lrow = lrow * scal + rs;

    asm volatile("" ::: "memory");

    __builtin_amdgcn_s_setprio(1);
#pragma unroll
    for (int ch = 0; ch < 4; ++ch) {
      int chunk = lg + (ch << 2);
      bf16x8 pb = *(const bf16x8*)((const char*)Pw + ll * 256 + ((chunk ^ (ll & 7)) << 4));
#pragma unroll
      for (int fd = 0; fd < 4; ++fd) {
        int dr = (fd << 4) + ll;
        bf16x8 av = *(const bf16x8*)((const char*)Vs + dr * 256 + ((chunk ^ (dr & 7)) << 4));
        oacc[fd] = __builtin_amdgcn_mfma_f32_16x16x32_bf16(av, pb, oacc[fd], 0, 0, 0);
      }
    }
    __builtin_amdgcn_s_setprio(0);

    if (kt < 7) {
      AT_SYNC;      // all waves done reading Vs/P
      WRITE_KV;     // vmcnt wait lands here (late)
      AT_SYNC;
    }
  }
#undef ISSUE_KV
#undef WRITE_KV

  float inv = 1.f / lrow;
#pragma unroll
  for (int fd = 0; fd < 4; ++fd) {
    f32x4 v = oacc[fd];
    int d0 = (fd << 4) + (lg << 2);
    u16* o = Og + (size_t)(tq0 + ll) * 768 + hh * 64 + d0;
    u32 lo = (u32)f2bf(v[0] * inv) | ((u32)f2bf(v[1] * inv) << 16);
    u32 hi = (u32)f2bf(v[2] * inv) | ((u32)f2bf(v[3] * inv) << 16);
    *(uint2*)o = make_uint2(lo, hi);
  }
}

// ---------- launch ----------
extern "C" void kernel_launch(void* const* d_in, const int* in_sizes, int n_in,
                              void* d_out, int out_size, void* d_ws, size_t ws_size,
                              hipStream_t stream) {
  const float* x = (const float*)d_in[0];
  const float* wq = (const float*)d_in[1];
  const float* wk = (const float*)d_in[2];
  const float* wv = (const float*)d_in[3];
  const float* wo = (const float*)d_in[4];
  const float* w1 = (const float*)d_in[5];
  const float* w2 = (const float*)d_in[6];
  const float* anw = (const float*)d_in[7];
  const float* fnw = (const float*)d_in[8];

  char* ws = (char*)d_ws;
  float* h    = (float*)(ws);
  u16* xn     = (u16*)(ws + 25165824);
  u16* qb     = (u16*)(ws + 37748736);
  u16* kb     = (u16*)(ws + 50331648);
  u16* vt     = (u16*)(ws + 62914560);
  u16* ff1    = (u16*)(ws + 75497472);
  u16* wbuf   = (u16*)(ws + 109051904);

  for (int L = 0; L < 12; ++L) {
    // per-layer convert = L2/L3 prefetch of this layer's weights
    convert_w<<<2688, 256, 0, stream>>>(
        wq + (size_t)L * 589824, wk + (size_t)L * 589824,
        wv + (size_t)L * 589824, wo + (size_t)L * 589824,
        w1 + (size_t)L * 1572864, w2 + (size_t)L * 1572864, wbuf);
    const float* hin = (L == 0) ? x : h;
    rmsnorm_k<<<2048, 256, 0, stream>>>(hin, anw + L * 768, xn);
    gemm_qkv<<<1152, 256, 0, stream>>>(xn, wbuf, qb, kb, vt);
    attn_kernel<<<1536, 256, 0, stream>>>(qb, kb, vt, qb);
    gemm_bt64<<<768, 256, 0, stream>>>(qb, wbuf + 1769472, h, hin, 8192, 768, 768);
    rmsnorm_k<<<2048, 256, 0, stream>>>(h, fnw + L * 768, xn);
    gemm_bt<2><<<1024, 256, 0, stream>>>(xn, wbuf + 2359296, ff1, nullptr, 8192, 2048, 768);
    float* outw = (L == 11) ? (float*)d_out : h;
    gemm_bt64<<<768, 256, 0, stream>>>(ff1, wbuf + 3932160, outw, h, 8192, 768, 2048);
  }
}

// Round 21
// 2475.172 us; speedup vs baseline: 1.1062x; 1.0112x over previous
//
#include <hip/hip_runtime.h>
#include <stdint.h>

typedef unsigned short u16;
typedef unsigned int u32;
typedef __bf16 bf16x8 __attribute__((ext_vector_type(8)));
typedef __bf16 bf16x4 __attribute__((ext_vector_type(4)));
typedef float f32x4 __attribute__((ext_vector_type(4)));

// ---------- helpers ----------
__device__ __forceinline__ u16 f2bf(float f) {
  u32 u = __builtin_bit_cast(u32, f);
  u32 r = (u + 0x7FFFu + ((u >> 16) & 1u)) >> 16;
  return (u16)r;
}

// ---------- weight fp32 -> bf16 (one layer; runs right before use = L2/L3 prefetch) ----------
__global__ __launch_bounds__(256)
void convert_w(const float* __restrict__ wq, const float* __restrict__ wk,
               const float* __restrict__ wv, const float* __restrict__ wo,
               const float* __restrict__ w1, const float* __restrict__ w2,
               u16* __restrict__ out) {
  size_t i = ((size_t)blockIdx.x * 256 + threadIdx.x) * 8;
  if (i >= 5505024) return;
  const float* src; size_t off;
  if (i < 589824)       { src = wq; off = i; }
  else if (i < 1179648) { src = wk; off = i - 589824; }
  else if (i < 1769472) { src = wv; off = i - 1179648; }
  else if (i < 2359296) { src = wo; off = i - 1769472; }
  else if (i < 3932160) { src = w1; off = i - 2359296; }
  else                  { src = w2; off = i - 3932160; }
  float4 a = *(const float4*)(src + off);
  float4 b = *(const float4*)(src + off + 4);
  uint4 o;
  o.x = (u32)f2bf(a.x) | ((u32)f2bf(a.y) << 16);
  o.y = (u32)f2bf(a.z) | ((u32)f2bf(a.w) << 16);
  o.z = (u32)f2bf(b.x) | ((u32)f2bf(b.y) << 16);
  o.w = (u32)f2bf(b.z) | ((u32)f2bf(b.w) << 16);
  *(uint4*)(out + i) = o;
}

// ---------- RMSNorm fp32 -> bf16 (D=768) ----------
__device__ __forceinline__ void rn_store4(u16* p, float4 v, float4 w, float sc) {
  u32 lo = (u32)f2bf(v.x * sc * w.x) | ((u32)f2bf(v.y * sc * w.y) << 16);
  u32 hi = (u32)f2bf(v.z * sc * w.z) | ((u32)f2bf(v.w * sc * w.w) << 16);
  *(uint2*)p = make_uint2(lo, hi);
}

__global__ __launch_bounds__(256)
void rmsnorm_k(const float* __restrict__ x, const float* __restrict__ w,
               u16* __restrict__ out) {
  const int tok = (blockIdx.x << 2) + (threadIdx.x >> 6);
  const int l = threadIdx.x & 63;
  const float* xr = x + (size_t)tok * 768;
  float4 v0 = *(const float4*)(xr + l * 4);
  float4 v1 = *(const float4*)(xr + 256 + l * 4);
  float4 v2 = *(const float4*)(xr + 512 + l * 4);
  float ss = v0.x*v0.x + v0.y*v0.y + v0.z*v0.z + v0.w*v0.w
           + v1.x*v1.x + v1.y*v1.y + v1.z*v1.z + v1.w*v1.w
           + v2.x*v2.x + v2.y*v2.y + v2.z*v2.z + v2.w*v2.w;
  ss += __shfl_xor(ss, 1);  ss += __shfl_xor(ss, 2);  ss += __shfl_xor(ss, 4);
  ss += __shfl_xor(ss, 8);  ss += __shfl_xor(ss, 16); ss += __shfl_xor(ss, 32);
  float sc = rsqrtf(ss * (1.f / 768.f) + 1e-12f);
  float4 w0 = *(const float4*)(w + l * 4);
  float4 w1v = *(const float4*)(w + 256 + l * 4);
  float4 w2v = *(const float4*)(w + 512 + l * 4);
  u16* o = out + (size_t)tok * 768;
  rn_store4(o + l * 4, v0, w0, sc);
  rn_store4(o + 256 + l * 4, v1, w1v, sc);
  rn_store4(o + 512 + l * 4, v2, w2v, sc);
}

// ---------- T1 chunked XCD swizzle ----------
__device__ __forceinline__ int xcd_swz(int bid, int nwg) {
  if (nwg & 7) return bid;
  return (bid & 7) * (nwg >> 3) + (bid >> 3);
}

// ---------- GEMM core (128x128 tile, 4 waves, m97 structure) ----------
#define GEMM_CORE(A_, W_, K_, m0_, n0_)                                             \
  for (int kt = 0; kt < (K_); kt += 64) {                                           \
    __syncthreads();                                                                \
    _Pragma("unroll")                                                               \
    for (int ii = 0; ii < 4; ++ii) {                                                \
      int issue = (w << 2) + ii;                                                    \
      int r = (issue << 3) + (l >> 3);                                              \
      int c = (l & 7) ^ (r & 7);                                                    \
      __builtin_amdgcn_global_load_lds((A_) + (size_t)((m0_) + r) * (K_) + kt + c * 8, \
                                       As + issue * 512, 16, 0, 0);                 \
      __builtin_amdgcn_global_load_lds((W_) + (size_t)((n0_) + r) * (K_) + kt + c * 8, \
                                       Ws + issue * 512, 16, 0, 0);                 \
    }                                                                               \
    __syncthreads();                                                                \
    _Pragma("unroll")                                                               \
    for (int kc = 0; kc < 2; ++kc) {                                                \
      int chunk = lg + (kc << 2);                                                   \
      bf16x8 af[4], bfr[4];                                                         \
      _Pragma("unroll")                                                             \
      for (int i = 0; i < 4; ++i) {                                                 \
        int mr = (wm << 6) + (i << 4) + ll;                                         \
        af[i] = *(const bf16x8*)((const char*)As + mr * 128 + ((chunk ^ (mr & 7)) << 4)); \
        int nr = (wn << 6) + (i << 4) + ll;                                         \
        bfr[i] = *(const bf16x8*)((const char*)Ws + nr * 128 + ((chunk ^ (nr & 7)) << 4)); \
      }                                                                             \
      _Pragma("unroll")                                                             \
      for (int i = 0; i < 4; ++i)                                                   \
        _Pragma("unroll")                                                           \
        for (int j = 0; j < 4; ++j)                                                 \
          acc[i][j] = __builtin_amdgcn_mfma_f32_16x16x32_bf16(af[i], bfr[j], acc[i][j], 0, 0, 0); \
    }                                                                               \
  }

// ---------- generic BT GEMM (r18 config: (256,2)) ----------
template<int EP>
__global__ __launch_bounds__(256, 2)
void gemm_bt(const u16* __restrict__ A, const u16* __restrict__ W,
             void* __restrict__ outp, const float* __restrict__ Res,
             int M, int N, int K) {
  __shared__ __align__(16) u16 As[128 * 64];
  __shared__ __align__(16) u16 Ws[128 * 64];
  const int tid = threadIdx.x;
  const int w = tid >> 6, l = tid & 63;
  const int lg = l >> 4, ll = l & 15;
  const int ntiles = N >> 7;
  const int wg = xcd_swz(blockIdx.x, gridDim.x);
  const int mt = wg / ntiles, nt = wg - mt * ntiles;
  const int m0 = mt << 7, n0 = nt << 7;
  const int wm = w >> 1, wn = w & 1;

  const f32x4 fz = {0.f, 0.f, 0.f, 0.f};
  f32x4 acc[4][4];
#pragma unroll
  for (int i = 0; i < 4; ++i)
#pragma unroll
    for (int j = 0; j < 4; ++j) acc[i][j] = fz;

  GEMM_CORE(A, W, K, m0, n0)

  const int g4 = lg << 2;
#pragma unroll
  for (int i = 0; i < 4; ++i) {
#pragma unroll
    for (int j = 0; j < 4; ++j) {
      int row0 = m0 + (wm << 6) + (i << 4) + g4;
      int col = n0 + (wn << 6) + (j << 4) + ll;
      f32x4 v = acc[i][j];
      if (EP == 0) {
        u16* o = (u16*)outp;
#pragma unroll
        for (int e = 0; e < 4; ++e) o[(size_t)(row0 + e) * N + col] = f2bf(v[e]);
      } else if (EP == 1) {
        float* o = (float*)outp;
#pragma unroll
        for (int e = 0; e < 4; ++e) {
          size_t idx = (size_t)(row0 + e) * N + col;
          o[idx] = Res[idx] + v[e];
        }
      } else {
        u16* o = (u16*)outp;
#pragma unroll
        for (int e = 0; e < 4; ++e) {
          float xx = v[e];
          o[(size_t)(row0 + e) * N + col] = f2bf(xx / (1.f + __expf(-xx)));
        }
      }
    }
  }
}

// ---------- 64x128-tile BT GEMM, fp32-residual epilogue (wo / ffn2) ----------
__global__ __launch_bounds__(256, 4)
void gemm_bt64(const u16* __restrict__ A, const u16* __restrict__ W,
               float* __restrict__ outp, const float* __restrict__ Res,
               int M, int N, int K) {
  __shared__ __align__(16) u16 As[64 * 64];
  __shared__ __align__(16) u16 Ws[128 * 64];
  const int tid = threadIdx.x;
  const int w = tid >> 6, l = tid & 63;
  const int lg = l >> 4, ll = l & 15;
  const int ntiles = N >> 7;
  const int wg = xcd_swz(blockIdx.x, gridDim.x);
  const int mt = wg / ntiles, nt = wg - mt * ntiles;
  const int m0 = mt << 6, n0 = nt << 7;
  const int wm = w >> 1, wn = w & 1;

  const f32x4 fz = {0.f, 0.f, 0.f, 0.f};
  f32x4 acc[2][4];
#pragma unroll
  for (int i = 0; i < 2; ++i)
#pragma unroll
    for (int j = 0; j < 4; ++j) acc[i][j] = fz;

  for (int kt = 0; kt < K; kt += 64) {
    __syncthreads();
#pragma unroll
    for (int ii = 0; ii < 6; ++ii) {
      int issue = w * 6 + ii;
      if (issue < 8) {
        int r = (issue << 3) + (l >> 3);
        int c = (l & 7) ^ (r & 7);
        __builtin_amdgcn_global_load_lds(A + (size_t)(m0 + r) * K + kt + c * 8,
                                         As + issue * 512, 16, 0, 0);
      } else {
        int is2 = issue - 8;
        int r = (is2 << 3) + (l >> 3);
        int c = (l & 7) ^ (r & 7);
        __builtin_amdgcn_global_load_lds(W + (size_t)(n0 + r) * K + kt + c * 8,
                                         Ws + is2 * 512, 16, 0, 0);
      }
    }
    __syncthreads();
#pragma unroll
    for (int kc = 0; kc < 2; ++kc) {
      int chunk = lg + (kc << 2);
      bf16x8 af[2], bfr[4];
#pragma unroll
      for (int i = 0; i < 2; ++i) {
        int mr = (wm << 5) + (i << 4) + ll;
        af[i] = *(const bf16x8*)((const char*)As + mr * 128 + ((chunk ^ (mr & 7)) << 4));
      }
#pragma unroll
      for (int j = 0; j < 4; ++j) {
        int nr = (wn << 6) + (j << 4) + ll;
        bfr[j] = *(const bf16x8*)((const char*)Ws + nr * 128 + ((chunk ^ (nr & 7)) << 4));
      }
#pragma unroll
      for (int i = 0; i < 2; ++i)
#pragma unroll
        for (int j = 0; j < 4; ++j)
          acc[i][j] = __builtin_amdgcn_mfma_f32_16x16x32_bf16(af[i], bfr[j], acc[i][j], 0, 0, 0);
    }
  }

  const int g4 = lg << 2;
#pragma unroll
  for (int i = 0; i < 2; ++i) {
#pragma unroll
    for (int j = 0; j < 4; ++j) {
      int row0 = m0 + (wm << 5) + (i << 4) + g4;
      int col = n0 + (wn << 6) + (j << 4) + ll;
      f32x4 v = acc[i][j];
#pragma unroll
      for (int e = 0; e < 4; ++e) {
        size_t idx = (size_t)(row0 + e) * N + col;
        outp[idx] = Res[idx] + v[e];
      }
    }
  }
}

// ---------- fused QKV GEMM (r18 config: (256,2)) ----------
__global__ __launch_bounds__(256, 2)
void gemm_qkv(const u16* __restrict__ A, const u16* __restrict__ W,
              u16* __restrict__ Qo, u16* __restrict__ Ko, u16* __restrict__ Vo) {
  __shared__ __align__(16) u16 As[128 * 64];
  __shared__ __align__(16) u16 Ws[128 * 64];
  const int tid = threadIdx.x;
  const int w = tid >> 6, l = tid & 63;
  const int lg = l >> 4, ll = l & 15;
  const int wg = xcd_swz(blockIdx.x, 1152);
  const int mt = wg / 18, nt = wg - mt * 18;
  const int m0 = mt << 7, n0 = nt << 7;
  const int wm = w >> 1, wn = w & 1;
  const int K = 768;

  const f32x4 fz = {0.f, 0.f, 0.f, 0.f};
  f32x4 acc[4][4];
#pragma unroll
  for (int i = 0; i < 4; ++i)
#pragma unroll
    for (int j = 0; j < 4; ++j) acc[i][j] = fz;

  GEMM_CORE(A, W, K, m0, n0)

  const int g4 = lg << 2;
#pragma unroll
  for (int i = 0; i < 4; ++i) {
#pragma unroll
    for (int j = 0; j < 4; ++j) {
      int row0 = m0 + (wm << 6) + (i << 4) + g4;
      int col = n0 + (wn << 6) + (j << 4) + ll;
      f32x4 v = acc[i][j];
      if (nt < 12) {
        u16* o = (nt < 6) ? Qo : Ko;
        int c = (nt < 6) ? col : (col - 768);
#pragma unroll
        for (int e = 0; e < 4; ++e) o[(size_t)(row0 + e) * 768 + c] = f2bf(v[e]);
      } else {
        int c = col - 1536;
        int vrow = ((row0 >> 10) * 768) + c;
        u32 lo = (u32)f2bf(v[0]) | ((u32)f2bf(v[1]) << 16);
        u32 hi = (u32)f2bf(v[2]) | ((u32)f2bf(v[3]) << 16);
        *(uint2*)(Vo + ((size_t)vrow << 10) + (row0 & 1023)) = make_uint2(lo, hi);
      }
    }
  }
}

// ---------- flash attention: dedicated P buffer -> 2 barriers/tile ----------
// Runtime residency is capped at 2 blocks/CU by (256,2) regardless of LDS
// (32.8 vs 48 KB both fit), so the dedicated Ps is free and removes the
// post-QK^T barrier that the P-in-Ks aliasing required.
#define AT_SYNC  asm volatile("s_waitcnt lgkmcnt(0)" ::: "memory"); \
                 __builtin_amdgcn_s_barrier();                      \
                 asm volatile("" ::: "memory")
__global__ __launch_bounds__(256, 2)
void attn_kernel(const u16* __restrict__ Q, const u16* __restrict__ Kg,
                 const u16* __restrict__ Vt, u16* __restrict__ Og) {
  __shared__ __align__(16) __bf16 Ks[128 * 64];
  __shared__ __align__(16) __bf16 Vs[64 * 128];
  __shared__ __align__(16) __bf16 Ps[4][16 * 128];  // wave-private P

  const int tid = threadIdx.x;
  const int w = tid >> 6, l = tid & 63;
  const int lg = l >> 4, ll = l & 15;
  const int bid = blockIdx.x;
  const int qt = bid / 96;          // XCD-locality remap (96 % 8 == 0)
  const int bh = bid - (bid / 96) * 96;
  const int b = bh / 12, hh = bh - b * 12;
  const float SC = 0.125f * 1.44269504f;

  __bf16* Pw = &Ps[w][0];

  bf16x8 qf[2];
  const int tq0 = (b << 10) + (qt << 6) + (w << 4);
#pragma unroll
  for (int kc = 0; kc < 2; ++kc)
    qf[kc] = *(const bf16x8*)(Q + (size_t)(tq0 + ll) * 768 + hh * 64 + kc * 32 + lg * 8);

  bf16x8 kp[4], vp[4];
#define ISSUE_KV(t_)                                                                  \
  { _Pragma("unroll")                                                                 \
    for (int ii = 0; ii < 4; ++ii) {                                                  \
      int issue = (w << 2) + ii;                                                      \
      int r = (issue << 3) + (l >> 3);                                                \
      int c = (l & 7) ^ (r & 7);                                                      \
      kp[ii] = *(const bf16x8*)(Kg + (size_t)((b << 10) + ((t_) << 7) + r) * 768 + hh * 64 + c * 8); \
      int rv = (issue << 2) + (l >> 4);                                               \
      int cv = ll ^ (rv & 7);                                                         \
      vp[ii] = *(const bf16x8*)(Vt + (size_t)((bh << 6) + rv) * 1024 + ((t_) << 7) + cv * 8); \
    } }
#define WRITE_KV                                                                      \
  { _Pragma("unroll")                                                                 \
    for (int ii = 0; ii < 4; ++ii) {                                                  \
      int issue = (w << 2) + ii;                                                      \
      *(bf16x8*)((char*)Ks + issue * 1024 + l * 16) = kp[ii];                         \
      *(bf16x8*)((char*)Vs + issue * 1024 + l * 16) = vp[ii];                         \
    } }

  const f32x4 fz = {0.f, 0.f, 0.f, 0.f};
  f32x4 oacc[4];
#pragma unroll
  for (int i = 0; i < 4; ++i) oacc[i] = fz;
  float mrow = -1e30f, lrow = 0.f;

  ISSUE_KV(0);
  WRITE_KV;
  AT_SYNC;

  for (int kt = 0; kt < 8; ++kt) {
    if (kt < 7) ISSUE_KV(kt + 1);

    f32x4 sa[8];
#pragma unroll
    for (int fn = 0; fn < 8; ++fn) sa[fn] = fz;
    __builtin_amdgcn_s_setprio(1);
#pragma unroll
    for (int kc = 0; kc < 2; ++kc) {
      int chunk = lg + (kc << 2);
      bf16x8 kb[8];
#pragma unroll
      for (int fn = 0; fn < 8; ++fn) {
        int nr = (fn << 4) + ll;
        kb[fn] = *(const bf16x8*)((const char*)Ks + nr * 128 + ((chunk ^ (nr & 7)) << 4));
      }
#pragma unroll
      for (int fn = 0; fn < 8; ++fn)
        sa[fn] = __builtin_amdgcn_mfma_f32_16x16x32_bf16(kb[fn], qf[kc], sa[fn], 0, 0, 0);
    }
    __builtin_amdgcn_s_setprio(0);

    // NO barrier here: P is wave-private (dedicated buffer), Ks stays intact.

    f32x4 vm = sa[0];
#pragma unroll
    for (int fn = 1; fn < 8; ++fn) {
#pragma unroll
      for (int e = 0; e < 4; ++e) vm[e] = fmaxf(vm[e], sa[fn][e]);
    }
    float mx = fmaxf(fmaxf(vm[0], vm[1]), fmaxf(vm[2], vm[3]));
    mx = fmaxf(mx, __shfl_xor(mx, 16));
    mx = fmaxf(mx, __shfl_xor(mx, 32));

    // T13 defer-max: skip rescale when per-tile max growth <= 8
    float scal = 1.f;
    bool rescale = !__all(mx - mrow <= 8.f);
    if (rescale) {
      float mnew = fmaxf(mrow, mx);
      scal = __builtin_amdgcn_exp2f(SC * (mrow - mnew));
#pragma unroll
      for (int fd = 0; fd < 4; ++fd) oacc[fd] *= scal;
      mrow = mnew;
    }
    float c2 = mrow * SC;

    f32x4 vsum = fz;
#pragma unroll
    for (int fn = 0; fn < 8; ++fn) {
      f32x4 p;
#pragma unroll
      for (int e = 0; e < 4; ++e)
        p[e] = __builtin_amdgcn_exp2f(__builtin_fmaf(SC, sa[fn][e], -c2));
      vsum += p;
      bf16x4 pv4;
#pragma unroll
      for (int e = 0; e < 4; ++e) pv4[e] = (__bf16)p[e];
      int chunk = (fn << 1) + (lg >> 1);
      *(bf16x4*)((char*)Pw + ll * 256 + ((chunk ^ (ll & 7)) << 4) + ((lg & 1) << 3)) = pv4;
    }
    float rs = (vsum[0] + vsum[1]) + (vsum[2] + vsum[3]);
    rs += __shfl_xor(rs, 16);
    rs += __shfl_xor(rs, 32);
    lrow = lrow * scal + rs;

    asm volatile("" ::: "memory");  // order P writes before PV reads (same wave)

    __builtin_amdgcn_s_setprio(1);
#pragma unroll
    for (int ch = 0; ch < 4; ++ch) {
      int chunk = lg + (ch << 2);
      bf16x8 pb = *(const bf16x8*)((const char*)Pw + ll * 256 + ((chunk ^ (ll & 7)) << 4));
#pragma unroll
      for (int fd = 0; fd < 4; ++fd) {
        int dr = (fd << 4) + ll;
        bf16x8 av = *(const bf16x8*)((const char*)Vs + dr * 256 + ((chunk ^ (dr & 7)) << 4));
        oacc[fd] = __builtin_amdgcn_mfma_f32_16x16x32_bf16(av, pb, oacc[fd], 0, 0, 0);
      }
    }
    __builtin_amdgcn_s_setprio(0);

    if (kt < 7) {
      AT_SYNC;      // all waves done reading Ks/Vs
      WRITE_KV;     // vmcnt wait lands here (late)
      AT_SYNC;      // writes visible
    }
  }
#undef ISSUE_KV
#undef WRITE_KV

  float inv = 1.f / lrow;
#pragma unroll
  for (int fd = 0; fd < 4; ++fd) {
    f32x4 v = oacc[fd];
    int d0 = (fd << 4) + (lg << 2);
    u16* o = Og + (size_t)(tq0 + ll) * 768 + hh * 64 + d0;
    u32 lo = (u32)f2bf(v[0] * inv) | ((u32)f2bf(v[1] * inv) << 16);
    u32 hi = (u32)f2bf(v[2] * inv) | ((u32)f2bf(v[3] * inv) << 16);
    *(uint2*)o = make_uint2(lo, hi);
  }
}

// ---------- launch ----------
extern "C" void kernel_launch(void* const* d_in, const int* in_sizes, int n_in,
                              void* d_out, int out_size, void* d_ws, size_t ws_size,
                              hipStream_t stream) {
  const float* x = (const float*)d_in[0];
  const float* wq = (const float*)d_in[1];
  const float* wk = (const float*)d_in[2];
  const float* wv = (const float*)d_in[3];
  const float* wo = (const float*)d_in[4];
  const float* w1 = (const float*)d_in[5];
  const float* w2 = (const float*)d_in[6];
  const float* anw = (const float*)d_in[7];
  const float* fnw = (const float*)d_in[8];

  char* ws = (char*)d_ws;
  float* h    = (float*)(ws);
  u16* xn     = (u16*)(ws + 25165824);
  u16* qb     = (u16*)(ws + 37748736);
  u16* kb     = (u16*)(ws + 50331648);
  u16* vt     = (u16*)(ws + 62914560);
  u16* ff1    = (u16*)(ws + 75497472);
  u16* wbuf   = (u16*)(ws + 109051904);

  for (int L = 0; L < 12; ++L) {
    // per-layer convert = L2/L3 prefetch of this layer's weights
    convert_w<<<2688, 256, 0, stream>>>(
        wq + (size_t)L * 589824, wk + (size_t)L * 589824,
        wv + (size_t)L * 589824, wo + (size_t)L * 589824,
        w1 + (size_t)L * 1572864, w2 + (size_t)L * 1572864, wbuf);
    const float* hin = (L == 0) ? x : h;
    rmsnorm_k<<<2048, 256, 0, stream>>>(hin, anw + L * 768, xn);
    gemm_qkv<<<1152, 256, 0, stream>>>(xn, wbuf, qb, kb, vt);
    attn_kernel<<<1536, 256, 0, stream>>>(qb, kb, vt, qb);
    gemm_bt64<<<768, 256, 0, stream>>>(qb, wbuf + 1769472, h, hin, 8192, 768, 768);
    rmsnorm_k<<<2048, 256, 0, stream>>>(h, fnw + L * 768, xn);
    gemm_bt<2><<<1024, 256, 0, stream>>>(xn, wbuf + 2359296, ff1, nullptr, 8192, 2048, 768);
    float* outw = (L == 11) ? (float*)d_out : h;
    gemm_bt64<<<768, 256, 0, stream>>>(ff1, wbuf + 3932160, outw, h, 8192, 768, 2048);
  }
}